// Round 13
// baseline (15294.534 us; speedup 1.0000x reference)
//
#include <hip/hip_runtime.h>

typedef _Float16 f16;
typedef f16 h8v __attribute__((ext_vector_type(8)));
typedef f16 h4v __attribute__((ext_vector_type(4)));
typedef float f4v __attribute__((ext_vector_type(4)));

#define TT 200
#define NTHR 512
#define NWG 256

// ---- d_ws layout (f16-element offsets) ----
#define W0F   0          // w_hh0  frag [64 tiles][512 h8v]
#define W1IF  262144     // w_ih1
#define W1HF  524288     // w_hh1
#define OW1F  786432     // out_w1 frag [8 tiles] -- read from global in the head (L2-hot)
#define EW2F  819200     // enc_w2 frag [16 tiles]
#define EW3F  884736     // enc_w3 frag [16 tiles]
#define HIWF  950272     // hinit_w frag [32 tiles]
#define CIWF  1081344    // cinit_w frag [32 tiles]
#define FRAG_TOTAL 1212416  // == CIWF + 131072; conv_w must cover ALL of it
#define H0F   1212416    // h0 state [2 parity][16 g][16 m][512][16] f16
#define H1F   5406720    // h1 state (same shape)
#define FLGF  10780672   // int32 flags [16 g][8] at byte offset FLGF*2

// flag indices
#define FE1 0
#define FE2 1
#define FE3 2
#define FDEC 3
#define FH0 4
#define FH1 5

static __device__ __forceinline__ f4v mfma16(h8v a, h8v b, f4v c) {
  return __builtin_amdgcn_mfma_f32_16x16x32_f16(a, b, c, 0, 0, 0);
}
static __device__ __forceinline__ f4v fzero() { f4v z; z[0]=0.f; z[1]=0.f; z[2]=0.f; z[3]=0.f; return z; }
// fast-rcp transcendentals (v_rcp_f32 ~1ulp; budget is 2e-3 -> fine)
static __device__ __forceinline__ float rcpf(float x) { return __builtin_amdgcn_rcpf(x); }
static __device__ __forceinline__ float sigm(float x) { return rcpf(1.0f + __expf(-x)); }
static __device__ __forceinline__ float tanh2(float x) { return 1.0f - 2.0f * rcpf(1.0f + __expf(2.0f * x)); }

// Fragment-order convert all 8 weight matrices (layout [tile][kc 32][lr 16] of h8v)
// and zero the group flags.
__global__ void conv_w(const float* __restrict__ whh0, const float* __restrict__ wih1,
                       const float* __restrict__ whh1, const float* __restrict__ ow1,
                       const float* __restrict__ ew2,  const float* __restrict__ ew3,
                       const float* __restrict__ hiw,  const float* __restrict__ ciw,
                       f16* __restrict__ dst, int* __restrict__ flags) {
  int i = blockIdx.x * 256 + threadIdx.x;   // 0 .. FRAG_TOTAL-1
  if (blockIdx.x == 0 && threadIdx.x < 128) flags[threadIdx.x] = 0;
  if (i >= FRAG_TOTAL) return;
  const float* src; int base;
  if      (i < 262144)  { src = whh0; base = 0; }
  else if (i < 524288)  { src = wih1; base = 262144; }
  else if (i < 786432)  { src = whh1; base = 524288; }
  else if (i < 819200)  { src = ow1;  base = 786432; }
  else if (i < 884736)  { src = ew2;  base = 819200; }
  else if (i < 950272)  { src = ew3;  base = 884736; }
  else if (i < 1081344) { src = hiw;  base = 950272; }
  else                  { src = ciw;  base = 1081344; }
  int e = i - base;
  int row = e >> 8, col = e & 255;
  int idx = base + ((((row >> 4) << 5) + (col >> 3)) << 7) + ((row & 15) << 3) + (col & 7);
  dst[idx] = (f16)src[e];
}

// group-flag protocol (AGENT scope; R11's relaxed-release pass proves same-XCD L2
// sharing for the bid%8 grouping, so agent-scope acquire/L1-inv suffices).
#define RELF(fi)                                                               \
  do { __syncthreads();                                                        \
       if (tid == 0) __hip_atomic_fetch_add(&flg[fi], 1, __ATOMIC_RELAXED,     \
                                            __HIP_MEMORY_SCOPE_AGENT);         \
  } while (0)
#define WAITF(fi, tgt)                                                         \
  do { if (tid == 0) {                                                         \
         while (__hip_atomic_load(&flg[fi], __ATOMIC_RELAXED,                  \
                                  __HIP_MEMORY_SCOPE_AGENT) < (tgt))           \
           __builtin_amdgcn_s_sleep(1);                                        \
         (void)__hip_atomic_load(&flg[fi], __ATOMIC_ACQUIRE,                   \
                                 __HIP_MEMORY_SCOPE_AGENT);                    \
       }                                                                       \
       __syncthreads();                                                        \
  } while (0)

__global__ __launch_bounds__(NTHR, 1)
void traj_kernel(const float* __restrict__ x,
                 const float* __restrict__ ew1, const float* __restrict__ eb1,
                 const float* __restrict__ eb2, const float* __restrict__ eb3,
                 const float* __restrict__ hib, const float* __restrict__ cib,
                 const float* __restrict__ wih0,
                 const float* __restrict__ bih0, const float* __restrict__ bhh0,
                 const float* __restrict__ bih1, const float* __restrict__ bhh1,
                 const float* __restrict__ ob1, const float* __restrict__ ow2,
                 const float* __restrict__ ob2, const float* __restrict__ stok,
                 f16* __restrict__ ws, int* __restrict__ flags,
                 float* __restrict__ out)
{
  __shared__ __align__(16) f16 WL[12 * 4096];    // 96 KB weight tiles (W0, W1i, W1h)
  __shared__ __align__(16) float decsL[512 * 4]; // 8 KB dec (computed redundantly)
  __shared__ float w2s[384];
  __shared__ float ob1L[128];                    // full out_b1
  __shared__ float b0L[64];                      // member-slice L0 biases [G][lr]
  __shared__ float b1L[64];                      // member-slice L1 biases
  __shared__ float wiL[192];                     // member-slice w_ih0 [G][lr][3]
  __shared__ float ob2s[4];

  const int tid  = threadIdx.x;
  const int bid  = blockIdx.x;
  const int g    = (bid & 7) + ((bid >> 7) << 3);   // 0..15
  const int m    = (bid >> 3) & 15;                 // member 0..15 (same bid%8 -> same XCD)
  const int wv   = tid >> 6;
  const int lane = tid & 63;
  const int lr   = lane & 15;
  const int lg   = lane >> 4;

  int* flg = flags + g * 8;
  const int dcol = 16 * m + lr;

  f16* e1g = ws + H0F + g * 131072;
  f16* e2g = ws + H1F + g * 131072;
  f16* e3g = ws + H0F + (16 + g) * 131072;

  // ---- per-lane constants -> LDS (keeps VGPR pressure under the 128 wall) ----
  if (tid < 64) {
    const int G = tid >> 4, l = tid & 15;
    const int gc = G * 256 + 16 * m + l;
    b0L[tid] = bih0[gc] + bhh0[gc];
    b1L[tid] = bih1[gc] + bhh1[gc];
    wiL[tid * 3 + 0] = wih0[gc * 3 + 0];
    wiL[tid * 3 + 1] = wih0[gc * 3 + 1];
    wiL[tid * 3 + 2] = wih0[gc * 3 + 2];
  }
  if (tid < 384) w2s[tid] = ow2[tid];
  if (tid < 128) ob1L[tid] = ob1[tid];
  if (tid < 3)   ob2s[tid] = ob2[tid];

  auto cptile = [&](int slot, int srcF) {
    ((h8v*)(WL + slot * 4096))[tid] = *(const h8v*)(ws + srcF + tid * 8);
  };
  auto BF = [&](int slot, int k) -> h8v {
    return ((const h8v*)WL)[slot * 512 + ((k << 2) + lg) * 16 + lr];
  };
  auto loadA8 = [&](const f16* gb, int R0, h8v* a) {
    const f16* p0 = gb + (lg >> 1) * 8192 + (size_t)(R0 + lr) * 16 + (lg & 1) * 8;
#pragma unroll
    for (int k = 0; k < 8; ++k) a[k] = *(const h8v*)(p0 + k * 16384);
  };

  // ================= setup: encoder + h/c init (exchange-based) =================
  cptile(0, EW2F + m * 4096);
  cptile(1, EW3F + m * 4096);
  cptile(2, HIWF + m * 4096);
  cptile(3, HIWF + (16 + m) * 4096);
  cptile(4, CIWF + m * 4096);
  cptile(5, CIWF + (16 + m) * 4096);
  __syncthreads();

  { // e1 (VALU)
    const int r = tid;
    float xr[7];
#pragma unroll
    for (int k = 0; k < 7; ++k) xr[k] = x[(size_t)(g * 512 + r) * 7 + k];
    f16 ev[16];
#pragma unroll
    for (int i2 = 0; i2 < 16; ++i2) {
      const int c = 16 * m + i2;
      float a = eb1[c];
#pragma unroll
      for (int k = 0; k < 7; ++k) a += xr[k] * ew1[c * 7 + k];
      ev[i2] = (f16)fmaxf(a, 0.0f);
    }
    *(h8v*)(e1g + m * 8192 + r * 16)     = *(h8v*)&ev[0];
    *(h8v*)(e1g + m * 8192 + r * 16 + 8) = *(h8v*)&ev[8];
  }
  RELF(FE1); WAITF(FE1, 16);

  { // e2 = relu(e1 @ ew2^T)
    const float bb = eb2[dcol];
#pragma unroll
    for (int mt = 0; mt < 4; ++mt) {
      const int R0 = wv * 64 + mt * 16;
      h8v a[8]; loadA8(e1g, R0, a);
      f4v acc = fzero();
#pragma unroll
      for (int k = 0; k < 8; ++k) acc = mfma16(a[k], BF(0, k), acc);
#pragma unroll
      for (int j = 0; j < 4; ++j)
        e2g[m * 8192 + (R0 + 4 * lg + j) * 16 + lr] = (f16)fmaxf(acc[j] + bb, 0.0f);
    }
  }
  RELF(FE2); WAITF(FE2, 16);

  { // e3 = relu(e2 @ ew3^T)
    const float bb = eb3[dcol];
#pragma unroll
    for (int mt = 0; mt < 4; ++mt) {
      const int R0 = wv * 64 + mt * 16;
      h8v a[8]; loadA8(e2g, R0, a);
      f4v acc = fzero();
#pragma unroll
      for (int k = 0; k < 8; ++k) acc = mfma16(a[k], BF(1, k), acc);
#pragma unroll
      for (int j = 0; j < 4; ++j)
        e3g[m * 8192 + (R0 + 4 * lg + j) * 16 + lr] = (f16)fmaxf(acc[j] + bb, 0.0f);
    }
  }
  RELF(FE3); WAITF(FE3, 16);

  // h/c init from e3
  float c0v[4][4], c1v[4][4];
  {
    f16* h0g0 = ws + H0F + g * 131072;   // parity-0 h0
    f16* h1g0 = ws + H1F + g * 131072;   // parity-0 h1
    const float bh0 = hib[dcol], bh1 = hib[256 + dcol];
    const float bc0 = cib[dcol], bc1 = cib[256 + dcol];
#pragma unroll
    for (int mt = 0; mt < 4; ++mt) {
      const int R0 = wv * 64 + mt * 16;
      h8v a[8]; loadA8(e3g, R0, a);
      f4v aH = fzero(), aC = fzero();
#pragma unroll
      for (int k = 0; k < 8; ++k) { aH = mfma16(a[k], BF(2, k), aH); aC = mfma16(a[k], BF(4, k), aC); }
#pragma unroll
      for (int j = 0; j < 4; ++j) {
        h0g0[m * 8192 + (R0 + 4 * lg + j) * 16 + lr] = (f16)(aH[j] + bh0);
        c0v[mt][j] = aC[j] + bc0;
      }
      aH = fzero(); aC = fzero();
#pragma unroll
      for (int k = 0; k < 8; ++k) { aH = mfma16(a[k], BF(3, k), aH); aC = mfma16(a[k], BF(5, k), aC); }
#pragma unroll
      for (int j = 0; j < 4; ++j) {
        h1g0[m * 8192 + (R0 + 4 * lg + j) * 16 + lr] = (f16)(aH[j] + bh1);
        c1v[mt][j] = aC[j] + bc1;
      }
    }
  }
  RELF(FDEC);

  // permanent weight tiles (W0, W1i, W1h only; OW1 stays in global/L2)
#pragma unroll
  for (int G = 0; G < 4; ++G) {
    cptile(G,     W0F  + (G * 16 + m) * 4096);
    cptile(4 + G, W1IF + (G * 16 + m) * 4096);
    cptile(8 + G, W1HF + (G * 16 + m) * 4096);
  }
  // dec(0) = start_token, locally
  {
    const float s0 = stok[0], s1 = stok[1], s2 = stok[2];
    decsL[tid * 4 + 0] = s0; decsL[tid * 4 + 1] = s1;
    decsL[tid * 4 + 2] = s2; decsL[tid * 4 + 3] = 0.f;
  }
  __syncthreads();

  // ---- prologue: all init state visible; precompute g0(0) = h0(0) @ W0 ----
  f4v g0a[4][4];
  WAITF(FDEC, 16);
  {
    const f16* h0old0 = ws + H0F + g * 131072;   // parity 0
#pragma unroll
    for (int mt = 0; mt < 4; ++mt) {
      const int R0 = wv * 64 + mt * 16;
      h8v a[8]; loadA8(h0old0, R0, a);
#pragma unroll
      for (int G = 0; G < 4; ++G) g0a[mt][G] = fzero();
#pragma unroll
      for (int k = 0; k < 8; ++k) {
        g0a[mt][0] = mfma16(a[k], BF(0, k), g0a[mt][0]);
        g0a[mt][1] = mfma16(a[k], BF(1, k), g0a[mt][1]);
        g0a[mt][2] = mfma16(a[k], BF(2, k), g0a[mt][2]);
        g0a[mt][3] = mfma16(a[k], BF(3, k), g0a[mt][3]);
      }
    }
  }

  // ================= T = 200 sequential decoder steps =================
  // 2 syncs/step (FH0, FH1). Head + dec computed REDUNDANTLY per member from
  // h1new against global OW1 (shared 64 KB, L2-hot) -- o1 never materializes,
  // so the FO1/FDEC syncs and the o1g exchange are gone (R12's regression was
  // 16x reads of per-step-fresh o1g; OW1 is immutable and stays L2-resident).
#pragma unroll 1
  for (int t = 0; t < TT; ++t) {
    const int p = t & 1;
    f16* h0new = ws + H0F + ((p ^ 1) * 16 + g) * 131072;
    f16* h1old = ws + H1F + (p * 16 + g) * 131072;
    f16* h1new = ws + H1F + ((p ^ 1) * 16 + g) * 131072;

    // (B) E0: consume g0a + decsL -> h0new
    {
      float cb0[4], cw[4][3];
#pragma unroll
      for (int G = 0; G < 4; ++G) {
        cb0[G]   = b0L[G * 16 + lr];
        cw[G][0] = wiL[(G * 16 + lr) * 3 + 0];
        cw[G][1] = wiL[(G * 16 + lr) * 3 + 1];
        cw[G][2] = wiL[(G * 16 + lr) * 3 + 2];
      }
#pragma unroll
      for (int mt = 0; mt < 4; ++mt) {
        const int R0 = wv * 64 + mt * 16;
#pragma unroll
        for (int j = 0; j < 4; ++j) {
          const int row = R0 + 4 * lg + j;
          f4v d4 = *(const f4v*)(decsL + row * 4);
          float gi = g0a[mt][0][j] + cb0[0] + d4[0]*cw[0][0] + d4[1]*cw[0][1] + d4[2]*cw[0][2];
          float gf = g0a[mt][1][j] + cb0[1] + d4[0]*cw[1][0] + d4[1]*cw[1][1] + d4[2]*cw[1][2];
          float gg = g0a[mt][2][j] + cb0[2] + d4[0]*cw[2][0] + d4[1]*cw[2][1] + d4[2]*cw[2][2];
          float go = g0a[mt][3][j] + cb0[3] + d4[0]*cw[3][0] + d4[1]*cw[3][1] + d4[2]*cw[3][2];
          float cn = sigm(gf) * c0v[mt][j] + sigm(gi) * tanh2(gg);
          c0v[mt][j] = cn;
          h0new[m * 8192 + row * 16 + lr] = (f16)(sigm(go) * tanh2(cn));
        }
      }
    }
    RELF(FH0);

    // (C) Phh mt0,1 = h1old @ W1h : covers the FH0 wait
    f4v ph[2][4];
#pragma unroll
    for (int mt = 0; mt < 2; ++mt) {
      const int R0 = wv * 64 + mt * 16;
      h8v a[8]; loadA8(h1old, R0, a);
#pragma unroll
      for (int G = 0; G < 4; ++G) ph[mt][G] = fzero();
#pragma unroll
      for (int k = 0; k < 8; ++k) {
        ph[mt][0] = mfma16(a[k], BF(8,  k), ph[mt][0]);
        ph[mt][1] = mfma16(a[k], BF(9,  k), ph[mt][1]);
        ph[mt][2] = mfma16(a[k], BF(10, k), ph[mt][2]);
        ph[mt][3] = mfma16(a[k], BF(11, k), ph[mt][3]);
      }
    }
    WAITF(FH0, 16 * (t + 1));

    // (D) L1
    {
      float cb1[4];
#pragma unroll
      for (int G = 0; G < 4; ++G) cb1[G] = b1L[G * 16 + lr];
      // mt 0,1: += W1i, then elementwise
#pragma unroll
      for (int mt = 0; mt < 2; ++mt) {
        const int R0 = wv * 64 + mt * 16;
        h8v a[8]; loadA8(h0new, R0, a);
#pragma unroll
        for (int k = 0; k < 8; ++k) {
          ph[mt][0] = mfma16(a[k], BF(4, k), ph[mt][0]);
          ph[mt][1] = mfma16(a[k], BF(5, k), ph[mt][1]);
          ph[mt][2] = mfma16(a[k], BF(6, k), ph[mt][2]);
          ph[mt][3] = mfma16(a[k], BF(7, k), ph[mt][3]);
        }
#pragma unroll
        for (int j = 0; j < 4; ++j) {
          const int row = R0 + 4 * lg + j;
          float cn = sigm(ph[mt][1][j] + cb1[1]) * c1v[mt][j]
                   + sigm(ph[mt][0][j] + cb1[0]) * tanh2(ph[mt][2][j] + cb1[2]);
          c1v[mt][j] = cn;
          h1new[m * 8192 + row * 16 + lr] = (f16)(sigm(ph[mt][3][j] + cb1[3]) * tanh2(cn));
        }
      }
      // mt 2,3: fresh accumulators, W1h + W1i
#pragma unroll
      for (int mt = 2; mt < 4; ++mt) {
        const int R0 = wv * 64 + mt * 16;
        f4v ai = fzero(), af = fzero(), ag = fzero(), ao = fzero();
        {
          h8v a[8]; loadA8(h1old, R0, a);
#pragma unroll
          for (int k = 0; k < 8; ++k) {
            ai = mfma16(a[k], BF(8,  k), ai);
            af = mfma16(a[k], BF(9,  k), af);
            ag = mfma16(a[k], BF(10, k), ag);
            ao = mfma16(a[k], BF(11, k), ao);
          }
        }
        {
          h8v a[8]; loadA8(h0new, R0, a);
#pragma unroll
          for (int k = 0; k < 8; ++k) {
            ai = mfma16(a[k], BF(4, k), ai);
            af = mfma16(a[k], BF(5, k), af);
            ag = mfma16(a[k], BF(6, k), ag);
            ao = mfma16(a[k], BF(7, k), ao);
          }
        }
#pragma unroll
        for (int j = 0; j < 4; ++j) {
          const int row = R0 + 4 * lg + j;
          float cn = sigm(af[j] + cb1[1]) * c1v[mt][j]
                   + sigm(ai[j] + cb1[0]) * tanh2(ag[j] + cb1[2]);
          c1v[mt][j] = cn;
          h1new[m * 8192 + row * 16 + lr] = (f16)(sigm(ao[j] + cb1[3]) * tanh2(cn));
        }
      }
    }
    RELF(FH1);

    // (E) g0(t+1) mt0 only = h0new @ W0 : covers the FH1 wait
    //     (16 regs live through the head instead of 32 -> no spill)
    {
      const int R0 = wv * 64;
      h8v a[8]; loadA8(h0new, R0, a);
#pragma unroll
      for (int G = 0; G < 4; ++G) g0a[0][G] = fzero();
#pragma unroll
      for (int k = 0; k < 8; ++k) {
        g0a[0][0] = mfma16(a[k], BF(0, k), g0a[0][0]);
        g0a[0][1] = mfma16(a[k], BF(1, k), g0a[0][1]);
        g0a[0][2] = mfma16(a[k], BF(2, k), g0a[0][2]);
        g0a[0][3] = mfma16(a[k], BF(3, k), g0a[0][3]);
      }
    }
    WAITF(FH1, 16 * (t + 1));

    // (F) head + dec, redundantly per member, all 512 rows:
    //     o1 = relu(h1new @ ow1^T + ob1) in registers; dec = o1 @ ow2^T + ob2.
    {
      const h8v* OW1G = (const h8v*)(ws + OW1F);
#pragma unroll
      for (int mt = 0; mt < 4; ++mt) {
        const int R0 = wv * 64 + mt * 16;
        h8v a[8]; loadA8(h1new, R0, a);
        f4v acc[8];
#pragma unroll
        for (int nt = 0; nt < 8; ++nt) acc[nt] = fzero();
#pragma unroll
        for (int k = 0; k < 8; ++k) {
          const int kc = ((k << 2) + lg) * 16 + lr;
#pragma unroll
          for (int nt = 0; nt < 8; ++nt)
            acc[nt] = mfma16(a[k], OW1G[nt * 512 + kc], acc[nt]);
        }
        float d0[4] = {0.f,0.f,0.f,0.f}, d1[4] = {0.f,0.f,0.f,0.f}, d2[4] = {0.f,0.f,0.f,0.f};
#pragma unroll
        for (int nt = 0; nt < 8; ++nt) {
          const int col = nt * 16 + lr;
          const float bo = ob1L[col];
          const float u0 = w2s[col], u1 = w2s[128 + col], u2 = w2s[256 + col];
#pragma unroll
          for (int j = 0; j < 4; ++j) {
            const float v = fmaxf(acc[nt][j] + bo, 0.0f);
            d0[j] += v * u0; d1[j] += v * u1; d2[j] += v * u2;
          }
        }
#pragma unroll
        for (int s = 8; s >= 1; s >>= 1) {
#pragma unroll
          for (int j = 0; j < 4; ++j) {
            d0[j] += __shfl_xor(d0[j], s);
            d1[j] += __shfl_xor(d1[j], s);
            d2[j] += __shfl_xor(d2[j], s);
          }
        }
        if (lr == 0) {
#pragma unroll
          for (int j = 0; j < 4; ++j) {
            const int row = R0 + 4 * lg + j;
            const float a0 = d0[j] + ob2s[0];
            const float a1 = d1[j] + ob2s[1];
            const float a2 = d2[j] + ob2s[2];
            decsL[row * 4 + 0] = a0;
            decsL[row * 4 + 1] = a1;
            decsL[row * 4 + 2] = a2;
            if ((row >> 5) == m) {
              float* op = out + ((size_t)(g * 512 + row) * TT + t) * 3;
              op[0] = a0; op[1] = a1; op[2] = a2;
            }
          }
        }
      }
    }

    // (G) g0(t+1) mt1,2,3
#pragma unroll
    for (int mt = 1; mt < 4; ++mt) {
      const int R0 = wv * 64 + mt * 16;
      h8v a[8]; loadA8(h0new, R0, a);
#pragma unroll
      for (int G = 0; G < 4; ++G) g0a[mt][G] = fzero();
#pragma unroll
      for (int k = 0; k < 8; ++k) {
        g0a[mt][0] = mfma16(a[k], BF(0, k), g0a[mt][0]);
        g0a[mt][1] = mfma16(a[k], BF(1, k), g0a[mt][1]);
        g0a[mt][2] = mfma16(a[k], BF(2, k), g0a[mt][2]);
        g0a[mt][3] = mfma16(a[k], BF(3, k), g0a[mt][3]);
      }
    }
    __syncthreads();   // decsL visible to all waves for next step's E0
  }
}

extern "C" void kernel_launch(void* const* d_in, const int* in_sizes, int n_in,
                              void* d_out, int out_size, void* d_ws, size_t ws_size,
                              hipStream_t stream) {
  (void)in_sizes; (void)n_in; (void)out_size; (void)ws_size;
  f16* wk = (f16*)d_ws;
  int* flags = (int*)((char*)d_ws + (size_t)FLGF * 2);
  conv_w<<<(FRAG_TOTAL + 255) / 256, 256, 0, stream>>>(
      (const float*)d_in[12], (const float*)d_in[15],
      (const float*)d_in[16], (const float*)d_in[19],
      (const float*)d_in[3],  (const float*)d_in[5],
      (const float*)d_in[7],  (const float*)d_in[9],
      wk, flags);
  traj_kernel<<<NWG, NTHR, 0, stream>>>(
      (const float*)d_in[0],
      (const float*)d_in[1],  (const float*)d_in[2],
      (const float*)d_in[4],  (const float*)d_in[6],
      (const float*)d_in[8],  (const float*)d_in[10],
      (const float*)d_in[11],
      (const float*)d_in[13], (const float*)d_in[14],
      (const float*)d_in[17], (const float*)d_in[18],
      (const float*)d_in[20], (const float*)d_in[21],
      (const float*)d_in[22], (const float*)d_in[23],
      wk, flags, (float*)d_out);
}

// Round 14
// 4706.672 us; speedup vs baseline: 3.2495x; 3.2495x over previous
//
#include <hip/hip_runtime.h>

typedef _Float16 f16;
typedef f16 h8v __attribute__((ext_vector_type(8)));
typedef f16 h4v __attribute__((ext_vector_type(4)));
typedef float f4v __attribute__((ext_vector_type(4)));

#define TT 200
#define NTHR 512
#define NWG 256

// ---- d_ws layout (f16-element offsets) ----
#define W0F   0          // w_hh0  frag [64 tiles][512 h8v]
#define W1IF  262144     // w_ih1
#define W1HF  524288     // w_hh1
#define OW1F  786432     // out_w1 frag [8 tiles] -- immutable, L2-hot, read in head
#define EW2F  819200     // enc_w2 frag [16 tiles]
#define EW3F  884736     // enc_w3 frag [16 tiles]
#define HIWF  950272     // hinit_w frag [32 tiles]
#define CIWF  1081344    // cinit_w frag [32 tiles]
#define FRAG_TOTAL 1212416  // == CIWF + 131072; conv_w must cover ALL of it
#define H0F   1212416    // h0 state [2 parity][16 g][16 m][512][16] f16
#define H1F   5406720    // h1 state (same shape)
#define DECF  9601024    // dec [16 g][2 parity][512][4] FLOAT (131072 f16 units)
#define FLGF  10780672   // int32 flags [16 g][8] at byte offset FLGF*2

// flag indices
#define FE1 0
#define FE2 1
#define FE3 2
#define FDEC 3
#define FH0 4
#define FH1 5

static __device__ __forceinline__ f4v mfma16(h8v a, h8v b, f4v c) {
  return __builtin_amdgcn_mfma_f32_16x16x32_f16(a, b, c, 0, 0, 0);
}
static __device__ __forceinline__ f4v fzero() { f4v z; z[0]=0.f; z[1]=0.f; z[2]=0.f; z[3]=0.f; return z; }
// fast-rcp transcendentals (v_rcp_f32 ~1ulp; budget is 2e-3 -> fine)
static __device__ __forceinline__ float rcpf(float x) { return __builtin_amdgcn_rcpf(x); }
static __device__ __forceinline__ float sigm(float x) { return rcpf(1.0f + __expf(-x)); }
static __device__ __forceinline__ float tanh2(float x) { return 1.0f - 2.0f * rcpf(1.0f + __expf(2.0f * x)); }

// Fragment-order convert all 8 weight matrices (layout [tile][kc 32][lr 16] of h8v)
// and zero the group flags.
__global__ void conv_w(const float* __restrict__ whh0, const float* __restrict__ wih1,
                       const float* __restrict__ whh1, const float* __restrict__ ow1,
                       const float* __restrict__ ew2,  const float* __restrict__ ew3,
                       const float* __restrict__ hiw,  const float* __restrict__ ciw,
                       f16* __restrict__ dst, int* __restrict__ flags) {
  int i = blockIdx.x * 256 + threadIdx.x;   // 0 .. FRAG_TOTAL-1
  if (blockIdx.x == 0 && threadIdx.x < 128) flags[threadIdx.x] = 0;
  if (i >= FRAG_TOTAL) return;
  const float* src; int base;
  if      (i < 262144)  { src = whh0; base = 0; }
  else if (i < 524288)  { src = wih1; base = 262144; }
  else if (i < 786432)  { src = whh1; base = 524288; }
  else if (i < 819200)  { src = ow1;  base = 786432; }
  else if (i < 884736)  { src = ew2;  base = 819200; }
  else if (i < 950272)  { src = ew3;  base = 884736; }
  else if (i < 1081344) { src = hiw;  base = 950272; }
  else                  { src = ciw;  base = 1081344; }
  int e = i - base;
  int row = e >> 8, col = e & 255;
  int idx = base + ((((row >> 4) << 5) + (col >> 3)) << 7) + ((row & 15) << 3) + (col & 7);
  dst[idx] = (f16)src[e];
}

// group-flag protocol (AGENT scope both sides):
//  R11's relaxed-release pass proves group members share an XCD L2 (a relaxed
//  release writes nothing back; readers could only have seen fresh data from the
//  shared L2). AGENT acquire provides the L1 invalidate needed for the parity-
//  buffer reuse WITHOUT invalidating L2 (SYSTEM acquire forced post-sync reads
//  to L3 -- the dominant cost in R11's 26 us/step). Correctness at AGENT scope
//  verified by R12/R13 (passed across ~140 dispatches).
#define RELF(fi)                                                               \
  do { __syncthreads();                                                        \
       if (tid == 0) __hip_atomic_fetch_add(&flg[fi], 1, __ATOMIC_RELAXED,     \
                                            __HIP_MEMORY_SCOPE_AGENT);         \
  } while (0)
#define WAITF(fi, tgt)                                                         \
  do { if (tid == 0) {                                                         \
         while (__hip_atomic_load(&flg[fi], __ATOMIC_RELAXED,                  \
                                  __HIP_MEMORY_SCOPE_AGENT) < (tgt))           \
           __builtin_amdgcn_s_sleep(1);                                        \
         (void)__hip_atomic_load(&flg[fi], __ATOMIC_ACQUIRE,                   \
                                 __HIP_MEMORY_SCOPE_AGENT);                    \
       }                                                                       \
       __syncthreads();                                                        \
  } while (0)

__global__ __launch_bounds__(NTHR, 1)
void traj_kernel(const float* __restrict__ x,
                 const float* __restrict__ ew1, const float* __restrict__ eb1,
                 const float* __restrict__ eb2, const float* __restrict__ eb3,
                 const float* __restrict__ hib, const float* __restrict__ cib,
                 const float* __restrict__ wih0,
                 const float* __restrict__ bih0, const float* __restrict__ bhh0,
                 const float* __restrict__ bih1, const float* __restrict__ bhh1,
                 const float* __restrict__ ob1, const float* __restrict__ ow2,
                 const float* __restrict__ ob2, const float* __restrict__ stok,
                 f16* __restrict__ ws, int* __restrict__ flags,
                 float* __restrict__ out)
{
  __shared__ __align__(16) f16 WL[12 * 4096];    // 96 KB weight tiles (W0, W1i, W1h)
  __shared__ __align__(16) float decsL[512 * 4]; // 8 KB dec stage (f32)
  __shared__ __align__(16) float o1s[32 * 132];  // 16.9 KB own-rows o1 (f32)
  __shared__ float w2s[384];
  __shared__ float ob1L[128];                    // full out_b1
  __shared__ float b0L[64];                      // member-slice L0 biases [G][lr]
  __shared__ float b1L[64];                      // member-slice L1 biases
  __shared__ float wiL[192];                     // member-slice w_ih0 [G][lr][3]
  __shared__ float ob2s[4];

  const int tid  = threadIdx.x;
  const int bid  = blockIdx.x;
  const int g    = (bid & 7) + ((bid >> 7) << 3);   // 0..15
  const int m    = (bid >> 3) & 15;                 // member 0..15 (same bid%8 -> same XCD)
  const int wv   = tid >> 6;
  const int lane = tid & 63;
  const int lr   = lane & 15;
  const int lg   = lane >> 4;

  int* flg = flags + g * 8;
  const int dcol = 16 * m + lr;

  f16* e1g = ws + H0F + g * 131072;
  f16* e2g = ws + H1F + g * 131072;
  f16* e3g = ws + H0F + (16 + g) * 131072;
  float* decb = (float*)(ws + DECF) + g * 4096;  // [2 parity][512][4] f32

  // ---- per-lane constants -> LDS (keeps VGPR pressure under the 128 wall) ----
  if (tid < 64) {
    const int G = tid >> 4, l = tid & 15;
    const int gc = G * 256 + 16 * m + l;
    b0L[tid] = bih0[gc] + bhh0[gc];
    b1L[tid] = bih1[gc] + bhh1[gc];
    wiL[tid * 3 + 0] = wih0[gc * 3 + 0];
    wiL[tid * 3 + 1] = wih0[gc * 3 + 1];
    wiL[tid * 3 + 2] = wih0[gc * 3 + 2];
  }
  if (tid < 384) w2s[tid] = ow2[tid];
  if (tid < 128) ob1L[tid] = ob1[tid];
  if (tid < 3)   ob2s[tid] = ob2[tid];

  auto cptile = [&](int slot, int srcF) {
    ((h8v*)(WL + slot * 4096))[tid] = *(const h8v*)(ws + srcF + tid * 8);
  };
  auto BF = [&](int slot, int k) -> h8v {
    return ((const h8v*)WL)[slot * 512 + ((k << 2) + lg) * 16 + lr];
  };
  auto loadA8 = [&](const f16* gb, int R0, h8v* a) {
    const f16* p0 = gb + (lg >> 1) * 8192 + (size_t)(R0 + lr) * 16 + (lg & 1) * 8;
#pragma unroll
    for (int k = 0; k < 8; ++k) a[k] = *(const h8v*)(p0 + k * 16384);
  };

  // ================= setup: encoder + h/c init (exchange-based) =================
  cptile(0, EW2F + m * 4096);
  cptile(1, EW3F + m * 4096);
  cptile(2, HIWF + m * 4096);
  cptile(3, HIWF + (16 + m) * 4096);
  cptile(4, CIWF + m * 4096);
  cptile(5, CIWF + (16 + m) * 4096);
  __syncthreads();

  { // e1 (VALU)
    const int r = tid;
    float xr[7];
#pragma unroll
    for (int k = 0; k < 7; ++k) xr[k] = x[(size_t)(g * 512 + r) * 7 + k];
    f16 ev[16];
#pragma unroll
    for (int i2 = 0; i2 < 16; ++i2) {
      const int c = 16 * m + i2;
      float a = eb1[c];
#pragma unroll
      for (int k = 0; k < 7; ++k) a += xr[k] * ew1[c * 7 + k];
      ev[i2] = (f16)fmaxf(a, 0.0f);
    }
    *(h8v*)(e1g + m * 8192 + r * 16)     = *(h8v*)&ev[0];
    *(h8v*)(e1g + m * 8192 + r * 16 + 8) = *(h8v*)&ev[8];
  }
  RELF(FE1); WAITF(FE1, 16);

  { // e2 = relu(e1 @ ew2^T)
    const float bb = eb2[dcol];
#pragma unroll
    for (int mt = 0; mt < 4; ++mt) {
      const int R0 = wv * 64 + mt * 16;
      h8v a[8]; loadA8(e1g, R0, a);
      f4v acc = fzero();
#pragma unroll
      for (int k = 0; k < 8; ++k) acc = mfma16(a[k], BF(0, k), acc);
#pragma unroll
      for (int j = 0; j < 4; ++j)
        e2g[m * 8192 + (R0 + 4 * lg + j) * 16 + lr] = (f16)fmaxf(acc[j] + bb, 0.0f);
    }
  }
  RELF(FE2); WAITF(FE2, 16);

  { // e3 = relu(e2 @ ew3^T)
    const float bb = eb3[dcol];
#pragma unroll
    for (int mt = 0; mt < 4; ++mt) {
      const int R0 = wv * 64 + mt * 16;
      h8v a[8]; loadA8(e2g, R0, a);
      f4v acc = fzero();
#pragma unroll
      for (int k = 0; k < 8; ++k) acc = mfma16(a[k], BF(1, k), acc);
#pragma unroll
      for (int j = 0; j < 4; ++j)
        e3g[m * 8192 + (R0 + 4 * lg + j) * 16 + lr] = (f16)fmaxf(acc[j] + bb, 0.0f);
    }
  }
  RELF(FE3); WAITF(FE3, 16);

  // h/c init from e3
  float c0v[4][4], c1v[4][4];
  {
    f16* h0g0 = ws + H0F + g * 131072;   // parity-0 h0
    f16* h1g0 = ws + H1F + g * 131072;   // parity-0 h1
    const float bh0 = hib[dcol], bh1 = hib[256 + dcol];
    const float bc0 = cib[dcol], bc1 = cib[256 + dcol];
#pragma unroll
    for (int mt = 0; mt < 4; ++mt) {
      const int R0 = wv * 64 + mt * 16;
      h8v a[8]; loadA8(e3g, R0, a);
      f4v aH = fzero(), aC = fzero();
#pragma unroll
      for (int k = 0; k < 8; ++k) { aH = mfma16(a[k], BF(2, k), aH); aC = mfma16(a[k], BF(4, k), aC); }
#pragma unroll
      for (int j = 0; j < 4; ++j) {
        h0g0[m * 8192 + (R0 + 4 * lg + j) * 16 + lr] = (f16)(aH[j] + bh0);
        c0v[mt][j] = aC[j] + bc0;
      }
      aH = fzero(); aC = fzero();
#pragma unroll
      for (int k = 0; k < 8; ++k) { aH = mfma16(a[k], BF(3, k), aH); aC = mfma16(a[k], BF(5, k), aC); }
#pragma unroll
      for (int j = 0; j < 4; ++j) {
        h1g0[m * 8192 + (R0 + 4 * lg + j) * 16 + lr] = (f16)(aH[j] + bh1);
        c1v[mt][j] = aC[j] + bc1;
      }
    }
    if (tid < 32) { // dec(0) = start_token (parity 0, f32)
      f4v d; d[0] = stok[0]; d[1] = stok[1]; d[2] = stok[2]; d[3] = 0.f;
      *(f4v*)(decb + (m * 32 + tid) * 4) = d;
    }
  }
  RELF(FDEC);

  // permanent weight tiles (W0, W1i, W1h; OW1 stays in global/L2)
#pragma unroll
  for (int G = 0; G < 4; ++G) {
    cptile(G,     W0F  + (G * 16 + m) * 4096);
    cptile(4 + G, W1IF + (G * 16 + m) * 4096);
    cptile(8 + G, W1HF + (G * 16 + m) * 4096);
  }
  __syncthreads();

  // ---- prologue: all init state visible; precompute g0(0) = h0(0) @ W0 ----
  f4v g0a[4][4];
  WAITF(FDEC, 16);
  {
    const f16* h0old0 = ws + H0F + g * 131072;   // parity 0
#pragma unroll
    for (int mt = 0; mt < 4; ++mt) {
      const int R0 = wv * 64 + mt * 16;
      h8v a[8]; loadA8(h0old0, R0, a);
#pragma unroll
      for (int G = 0; G < 4; ++G) g0a[mt][G] = fzero();
#pragma unroll
      for (int k = 0; k < 8; ++k) {
        g0a[mt][0] = mfma16(a[k], BF(0, k), g0a[mt][0]);
        g0a[mt][1] = mfma16(a[k], BF(1, k), g0a[mt][1]);
        g0a[mt][2] = mfma16(a[k], BF(2, k), g0a[mt][2]);
        g0a[mt][3] = mfma16(a[k], BF(3, k), g0a[mt][3]);
      }
    }
  }

  // ================= T = 200 sequential decoder steps =================
  // 3 syncs/step (FH0, FH1, FDEC). Head computes o1 for the member's OWN 32 rows
  // only (16 KB fresh h1new + 64 KB immutable OW1, L2-hot) -> no FO1 sync, no
  // redundant fresh-data reads (R12/R13 lesson). Cover schedule:
  //   FDEC <- g0 mt3 ; FH0 <- Phh mt0,1 ; FH1 <- g0 mt0,1.
#pragma unroll 1
  for (int t = 0; t < TT; ++t) {
    const int p = t & 1;
    f16* h0new = ws + H0F + ((p ^ 1) * 16 + g) * 131072;
    f16* h1old = ws + H1F + (p * 16 + g) * 131072;
    f16* h1new = ws + H1F + ((p ^ 1) * 16 + g) * 131072;
    const float* decp = decb + p * 2048;
    float* decn = decb + (p ^ 1) * 2048;

    // (A) dec ready (covered by g0 mt3 of previous iteration)
    WAITF(FDEC, 16 * (t + 1));
    *(f4v*)(decsL + tid * 4) = *(const f4v*)(decp + tid * 4);
    __syncthreads();

    // (B) E0: consume g0a + decsL -> h0new
    {
      float cb0[4], cw[4][3];
#pragma unroll
      for (int G = 0; G < 4; ++G) {
        cb0[G]   = b0L[G * 16 + lr];
        cw[G][0] = wiL[(G * 16 + lr) * 3 + 0];
        cw[G][1] = wiL[(G * 16 + lr) * 3 + 1];
        cw[G][2] = wiL[(G * 16 + lr) * 3 + 2];
      }
#pragma unroll
      for (int mt = 0; mt < 4; ++mt) {
        const int R0 = wv * 64 + mt * 16;
#pragma unroll
        for (int j = 0; j < 4; ++j) {
          const int row = R0 + 4 * lg + j;
          f4v d4 = *(const f4v*)(decsL + row * 4);
          float gi = g0a[mt][0][j] + cb0[0] + d4[0]*cw[0][0] + d4[1]*cw[0][1] + d4[2]*cw[0][2];
          float gf = g0a[mt][1][j] + cb0[1] + d4[0]*cw[1][0] + d4[1]*cw[1][1] + d4[2]*cw[1][2];
          float gg = g0a[mt][2][j] + cb0[2] + d4[0]*cw[2][0] + d4[1]*cw[2][1] + d4[2]*cw[2][2];
          float go = g0a[mt][3][j] + cb0[3] + d4[0]*cw[3][0] + d4[1]*cw[3][1] + d4[2]*cw[3][2];
          float cn = sigm(gf) * c0v[mt][j] + sigm(gi) * tanh2(gg);
          c0v[mt][j] = cn;
          h0new[m * 8192 + row * 16 + lr] = (f16)(sigm(go) * tanh2(cn));
        }
      }
    }
    RELF(FH0);

    // (C) Phh mt0,1 = h1old @ W1h : covers the FH0 wait
    f4v ph[2][4];
#pragma unroll
    for (int mt = 0; mt < 2; ++mt) {
      const int R0 = wv * 64 + mt * 16;
      h8v a[8]; loadA8(h1old, R0, a);
#pragma unroll
      for (int G = 0; G < 4; ++G) ph[mt][G] = fzero();
#pragma unroll
      for (int k = 0; k < 8; ++k) {
        ph[mt][0] = mfma16(a[k], BF(8,  k), ph[mt][0]);
        ph[mt][1] = mfma16(a[k], BF(9,  k), ph[mt][1]);
        ph[mt][2] = mfma16(a[k], BF(10, k), ph[mt][2]);
        ph[mt][3] = mfma16(a[k], BF(11, k), ph[mt][3]);
      }
    }
    WAITF(FH0, 16 * (t + 1));

    // (D) L1
    {
      float cb1[4];
#pragma unroll
      for (int G = 0; G < 4; ++G) cb1[G] = b1L[G * 16 + lr];
      // mt 0,1: += W1i, then elementwise
#pragma unroll
      for (int mt = 0; mt < 2; ++mt) {
        const int R0 = wv * 64 + mt * 16;
        h8v a[8]; loadA8(h0new, R0, a);
#pragma unroll
        for (int k = 0; k < 8; ++k) {
          ph[mt][0] = mfma16(a[k], BF(4, k), ph[mt][0]);
          ph[mt][1] = mfma16(a[k], BF(5, k), ph[mt][1]);
          ph[mt][2] = mfma16(a[k], BF(6, k), ph[mt][2]);
          ph[mt][3] = mfma16(a[k], BF(7, k), ph[mt][3]);
        }
#pragma unroll
        for (int j = 0; j < 4; ++j) {
          const int row = R0 + 4 * lg + j;
          float cn = sigm(ph[mt][1][j] + cb1[1]) * c1v[mt][j]
                   + sigm(ph[mt][0][j] + cb1[0]) * tanh2(ph[mt][2][j] + cb1[2]);
          c1v[mt][j] = cn;
          h1new[m * 8192 + row * 16 + lr] = (f16)(sigm(ph[mt][3][j] + cb1[3]) * tanh2(cn));
        }
      }
      // mt 2,3: fresh accumulators, W1h + W1i
#pragma unroll
      for (int mt = 2; mt < 4; ++mt) {
        const int R0 = wv * 64 + mt * 16;
        f4v ai = fzero(), af = fzero(), ag = fzero(), ao = fzero();
        {
          h8v a[8]; loadA8(h1old, R0, a);
#pragma unroll
          for (int k = 0; k < 8; ++k) {
            ai = mfma16(a[k], BF(8,  k), ai);
            af = mfma16(a[k], BF(9,  k), af);
            ag = mfma16(a[k], BF(10, k), ag);
            ao = mfma16(a[k], BF(11, k), ao);
          }
        }
        {
          h8v a[8]; loadA8(h0new, R0, a);
#pragma unroll
          for (int k = 0; k < 8; ++k) {
            ai = mfma16(a[k], BF(4, k), ai);
            af = mfma16(a[k], BF(5, k), af);
            ag = mfma16(a[k], BF(6, k), ag);
            ao = mfma16(a[k], BF(7, k), ao);
          }
        }
#pragma unroll
        for (int j = 0; j < 4; ++j) {
          const int row = R0 + 4 * lg + j;
          float cn = sigm(af[j] + cb1[1]) * c1v[mt][j]
                   + sigm(ai[j] + cb1[0]) * tanh2(ag[j] + cb1[2]);
          c1v[mt][j] = cn;
          h1new[m * 8192 + row * 16 + lr] = (f16)(sigm(ao[j] + cb1[3]) * tanh2(cn));
        }
      }
    }
    RELF(FH1);

    // (E) g0(t+1) mt0,1 = h0new @ W0 : covers the FH1 wait
#pragma unroll
    for (int mt = 0; mt < 2; ++mt) {
      const int R0 = wv * 64 + mt * 16;
      h8v a[8]; loadA8(h0new, R0, a);
#pragma unroll
      for (int G = 0; G < 4; ++G) g0a[mt][G] = fzero();
#pragma unroll
      for (int k = 0; k < 8; ++k) {
        g0a[mt][0] = mfma16(a[k], BF(0, k), g0a[mt][0]);
        g0a[mt][1] = mfma16(a[k], BF(1, k), g0a[mt][1]);
        g0a[mt][2] = mfma16(a[k], BF(2, k), g0a[mt][2]);
        g0a[mt][3] = mfma16(a[k], BF(3, k), g0a[mt][3]);
      }
    }
    WAITF(FH1, 16 * (t + 1));

    // (F) head: o1 = relu(h1new[own 32 rows] @ ow1^T + ob1) -> o1s (LDS, f32).
    //     Wave wv owns o1 col-tile wv; OW1 read from global (immutable, L2-hot).
    {
      const h8v* OW1G = (const h8v*)(ws + OW1F);
#pragma unroll
      for (int mt = 0; mt < 2; ++mt) {
        h8v a[8]; loadA8(h1new, m * 32 + mt * 16, a);
        f4v oacc = fzero();
#pragma unroll
        for (int k = 0; k < 8; ++k)
          oacc = mfma16(a[k], OW1G[(wv << 9) + (((k << 2) + lg) << 4) + lr], oacc);
        const float bo = ob1L[(wv << 4) + lr];
#pragma unroll
        for (int j = 0; j < 4; ++j)
          o1s[(mt * 16 + 4 * lg + j) * 132 + (wv << 4) + lr] = fmaxf(oacc[j] + bo, 0.0f);
      }
    }

    // (G) g0(t+1) mt2 rebuild (before the LDS barrier; independent of o1s)
    {
      const int R0 = wv * 64 + 2 * 16;
      h8v a[8]; loadA8(h0new, R0, a);
#pragma unroll
      for (int G = 0; G < 4; ++G) g0a[2][G] = fzero();
#pragma unroll
      for (int k = 0; k < 8; ++k) {
        g0a[2][0] = mfma16(a[k], BF(0, k), g0a[2][0]);
        g0a[2][1] = mfma16(a[k], BF(1, k), g0a[2][1]);
        g0a[2][2] = mfma16(a[k], BF(2, k), g0a[2][2]);
        g0a[2][3] = mfma16(a[k], BF(3, k), g0a[2][3]);
      }
    }
    __syncthreads();   // o1s visible

    // (H) dec GEMV over own 32 rows; write out + decn (global exchange)
    {
      const int r = tid >> 4, jj = tid & 15;   // 32 rows x 16 threads
      float a0 = 0.f, a1 = 0.f, a2 = 0.f;
#pragma unroll
      for (int kk = 0; kk < 8; ++kk) {
        const int k = jj * 8 + kk;
        const float ov = o1s[r * 132 + k];
        a0 += ov * w2s[k];
        a1 += ov * w2s[128 + k];
        a2 += ov * w2s[256 + k];
      }
#pragma unroll
      for (int s = 8; s >= 1; s >>= 1) {
        a0 += __shfl_xor(a0, s);
        a1 += __shfl_xor(a1, s);
        a2 += __shfl_xor(a2, s);
      }
      if (jj == 0) {
        a0 += ob2s[0]; a1 += ob2s[1]; a2 += ob2s[2];
        const int row = m * 32 + r;
        float* op = out + ((size_t)(g * 512 + row) * TT + t) * 3;
        op[0] = a0; op[1] = a1; op[2] = a2;
        f4v d; d[0] = a0; d[1] = a1; d[2] = a2; d[3] = 0.f;
        *(f4v*)(decn + row * 4) = d;
      }
    }
    RELF(FDEC);

    // (I) g0(t+1) mt3 : covers the next iteration's FDEC wait
    {
      const int R0 = wv * 64 + 3 * 16;
      h8v a[8]; loadA8(h0new, R0, a);
#pragma unroll
      for (int G = 0; G < 4; ++G) g0a[3][G] = fzero();
#pragma unroll
      for (int k = 0; k < 8; ++k) {
        g0a[3][0] = mfma16(a[k], BF(0, k), g0a[3][0]);
        g0a[3][1] = mfma16(a[k], BF(1, k), g0a[3][1]);
        g0a[3][2] = mfma16(a[k], BF(2, k), g0a[3][2]);
        g0a[3][3] = mfma16(a[k], BF(3, k), g0a[3][3]);
      }
    }
  }
}

extern "C" void kernel_launch(void* const* d_in, const int* in_sizes, int n_in,
                              void* d_out, int out_size, void* d_ws, size_t ws_size,
                              hipStream_t stream) {
  (void)in_sizes; (void)n_in; (void)out_size; (void)ws_size;
  f16* wk = (f16*)d_ws;
  int* flags = (int*)((char*)d_ws + (size_t)FLGF * 2);
  conv_w<<<(FRAG_TOTAL + 255) / 256, 256, 0, stream>>>(
      (const float*)d_in[12], (const float*)d_in[15],
      (const float*)d_in[16], (const float*)d_in[19],
      (const float*)d_in[3],  (const float*)d_in[5],
      (const float*)d_in[7],  (const float*)d_in[9],
      wk, flags);
  traj_kernel<<<NWG, NTHR, 0, stream>>>(
      (const float*)d_in[0],
      (const float*)d_in[1],  (const float*)d_in[2],
      (const float*)d_in[4],  (const float*)d_in[6],
      (const float*)d_in[8],  (const float*)d_in[10],
      (const float*)d_in[11],
      (const float*)d_in[13], (const float*)d_in[14],
      (const float*)d_in[17], (const float*)d_in[18],
      (const float*)d_in[20], (const float*)d_in[21],
      (const float*)d_in[22], (const float*)d_in[23],
      wk, flags, (float*)d_out);
}

// Round 15
// 4569.648 us; speedup vs baseline: 3.3470x; 1.0300x over previous
//
#include <hip/hip_runtime.h>

typedef _Float16 f16;
typedef f16 h8v __attribute__((ext_vector_type(8)));
typedef f16 h4v __attribute__((ext_vector_type(4)));
typedef float f4v __attribute__((ext_vector_type(4)));

#define TT 200
#define NTHR 512
#define NWG 256

// ---- d_ws layout (f16-element offsets) ----
#define W0F   0          // w_hh0  frag [64 tiles][512 h8v]
#define W1IF  262144     // w_ih1
#define W1HF  524288     // w_hh1
#define OW1F  786432     // out_w1 frag [8 tiles] -- immutable, L2-hot, read in head
#define EW2F  819200     // enc_w2 frag [16 tiles]
#define EW3F  884736     // enc_w3 frag [16 tiles]
#define HIWF  950272     // hinit_w frag [32 tiles]
#define CIWF  1081344    // cinit_w frag [32 tiles]
#define FRAG_TOTAL 1212416  // == CIWF + 131072; conv_w must cover ALL of it
#define H0F   1212416    // h0 state [2 parity][16 g][16 m][512][16] f16
#define H1F   5406720    // h1 state (same shape)
#define DECF  9601024    // dec [16 g][2 parity][512][4] FLOAT (131072 f16 units)
#define FLGF  10780672   // int32 flags [16 g][8 fi][16 m] at byte offset FLGF*2 (8 KB)

// flag indices
#define FE1 0
#define FE2 1
#define FE3 2
#define FDEC 3
#define FH0 4
#define FH1 5

static __device__ __forceinline__ f4v mfma16(h8v a, h8v b, f4v c) {
  return __builtin_amdgcn_mfma_f32_16x16x32_f16(a, b, c, 0, 0, 0);
}
static __device__ __forceinline__ f4v fzero() { f4v z; z[0]=0.f; z[1]=0.f; z[2]=0.f; z[3]=0.f; return z; }
// fast-rcp transcendentals (v_rcp_f32 ~1ulp; budget is 2e-3 -> fine)
static __device__ __forceinline__ float rcpf(float x) { return __builtin_amdgcn_rcpf(x); }
static __device__ __forceinline__ float sigm(float x) { return rcpf(1.0f + __expf(-x)); }
static __device__ __forceinline__ float tanh2(float x) { return 1.0f - 2.0f * rcpf(1.0f + __expf(2.0f * x)); }

// Fragment-order convert all 8 weight matrices (layout [tile][kc 32][lr 16] of h8v)
// and zero the group flags (now 2048 ints: 16 g x 8 fi x 16 m single-writer slots).
__global__ void conv_w(const float* __restrict__ whh0, const float* __restrict__ wih1,
                       const float* __restrict__ whh1, const float* __restrict__ ow1,
                       const float* __restrict__ ew2,  const float* __restrict__ ew3,
                       const float* __restrict__ hiw,  const float* __restrict__ ciw,
                       f16* __restrict__ dst, int* __restrict__ flags) {
  int i = blockIdx.x * 256 + threadIdx.x;   // 0 .. FRAG_TOTAL-1
  if (blockIdx.x < 8) flags[blockIdx.x * 256 + threadIdx.x] = 0;   // 2048 slots
  if (i >= FRAG_TOTAL) return;
  const float* src; int base;
  if      (i < 262144)  { src = whh0; base = 0; }
  else if (i < 524288)  { src = wih1; base = 262144; }
  else if (i < 786432)  { src = whh1; base = 524288; }
  else if (i < 819200)  { src = ow1;  base = 786432; }
  else if (i < 884736)  { src = ew2;  base = 819200; }
  else if (i < 950272)  { src = ew3;  base = 884736; }
  else if (i < 1081344) { src = hiw;  base = 950272; }
  else                  { src = ciw;  base = 1081344; }
  int e = i - base;
  int row = e >> 8, col = e & 255;
  int idx = base + ((((row >> 4) << 5) + (col >> 3)) << 7) + ((row & 15) << 3) + (col & 7);
  dst[idx] = (f16)src[e];
}

// group-flag protocol (AGENT scope, SINGLE-WRITER SLOTS):
//  R14's counters showed ~5 us/sync residual. Cause: 16 members' atomic_fetch_add
//  to ONE address serialize at the L2 coherence point (~100-150 cy each) -> the
//  16th release lands ~2 us after the first, inherited by every waiter (G12
//  applied to our own flags). Fix: member m STORES t+1 to its own slot (no RMW,
//  no serialization); waiter lanes 0-15 each poll one slot (16 slots = one 64B
//  line -> one coalesced load per poll), wave reconverges when all satisfied,
//  then one AGENT acquire + barrier. Payload ordering: __syncthreads before the
//  store drains vmcnt(0) (compiler-guaranteed), so payload is L2-visible first.
#define RELF(fi, val)                                                          \
  do { __syncthreads();                                                        \
       if (tid == 0) __hip_atomic_store(&flg[(fi) * 16 + m], (val),            \
                                        __ATOMIC_RELAXED,                      \
                                        __HIP_MEMORY_SCOPE_AGENT);             \
  } while (0)
#define WAITF(fi, tgt)                                                         \
  do { if (tid < 16) {                                                         \
         while (__hip_atomic_load(&flg[(fi) * 16 + tid], __ATOMIC_RELAXED,     \
                                  __HIP_MEMORY_SCOPE_AGENT) < (tgt))           \
           __builtin_amdgcn_s_sleep(1);                                        \
       }                                                                       \
       if (tid == 0)                                                           \
         (void)__hip_atomic_load(&flg[(fi) * 16], __ATOMIC_ACQUIRE,            \
                                 __HIP_MEMORY_SCOPE_AGENT);                    \
       __syncthreads();                                                        \
  } while (0)

__global__ __launch_bounds__(NTHR, 1)
void traj_kernel(const float* __restrict__ x,
                 const float* __restrict__ ew1, const float* __restrict__ eb1,
                 const float* __restrict__ eb2, const float* __restrict__ eb3,
                 const float* __restrict__ hib, const float* __restrict__ cib,
                 const float* __restrict__ wih0,
                 const float* __restrict__ bih0, const float* __restrict__ bhh0,
                 const float* __restrict__ bih1, const float* __restrict__ bhh1,
                 const float* __restrict__ ob1, const float* __restrict__ ow2,
                 const float* __restrict__ ob2, const float* __restrict__ stok,
                 f16* __restrict__ ws, int* __restrict__ flags,
                 float* __restrict__ out)
{
  __shared__ __align__(16) f16 WL[12 * 4096];    // 96 KB weight tiles (W0, W1i, W1h)
  __shared__ __align__(16) float decsL[512 * 4]; // 8 KB dec stage (f32)
  __shared__ __align__(16) float o1s[32 * 132];  // 16.9 KB own-rows o1 (f32)
  __shared__ float w2s[384];
  __shared__ float ob1L[128];                    // full out_b1
  __shared__ float b0L[64];                      // member-slice L0 biases [G][lr]
  __shared__ float b1L[64];                      // member-slice L1 biases
  __shared__ float wiL[192];                     // member-slice w_ih0 [G][lr][3]
  __shared__ float ob2s[4];

  const int tid  = threadIdx.x;
  const int bid  = blockIdx.x;
  const int g    = (bid & 7) + ((bid >> 7) << 3);   // 0..15
  const int m    = (bid >> 3) & 15;                 // member 0..15 (same bid%8 -> same XCD)
  const int wv   = tid >> 6;
  const int lane = tid & 63;
  const int lr   = lane & 15;
  const int lg   = lane >> 4;

  int* flg = flags + g * 128;                   // [8 fi][16 m]
  const int dcol = 16 * m + lr;

  f16* e1g = ws + H0F + g * 131072;
  f16* e2g = ws + H1F + g * 131072;
  f16* e3g = ws + H0F + (16 + g) * 131072;
  float* decb = (float*)(ws + DECF) + g * 4096;  // [2 parity][512][4] f32

  // ---- per-lane constants -> LDS (keeps VGPR pressure under the 128 wall) ----
  if (tid < 64) {
    const int G = tid >> 4, l = tid & 15;
    const int gc = G * 256 + 16 * m + l;
    b0L[tid] = bih0[gc] + bhh0[gc];
    b1L[tid] = bih1[gc] + bhh1[gc];
    wiL[tid * 3 + 0] = wih0[gc * 3 + 0];
    wiL[tid * 3 + 1] = wih0[gc * 3 + 1];
    wiL[tid * 3 + 2] = wih0[gc * 3 + 2];
  }
  if (tid < 384) w2s[tid] = ow2[tid];
  if (tid < 128) ob1L[tid] = ob1[tid];
  if (tid < 3)   ob2s[tid] = ob2[tid];

  auto cptile = [&](int slot, int srcF) {
    ((h8v*)(WL + slot * 4096))[tid] = *(const h8v*)(ws + srcF + tid * 8);
  };
  auto BF = [&](int slot, int k) -> h8v {
    return ((const h8v*)WL)[slot * 512 + ((k << 2) + lg) * 16 + lr];
  };
  auto loadA8 = [&](const f16* gb, int R0, h8v* a) {
    const f16* p0 = gb + (lg >> 1) * 8192 + (size_t)(R0 + lr) * 16 + (lg & 1) * 8;
#pragma unroll
    for (int k = 0; k < 8; ++k) a[k] = *(const h8v*)(p0 + k * 16384);
  };

  // ================= setup: encoder + h/c init (exchange-based) =================
  cptile(0, EW2F + m * 4096);
  cptile(1, EW3F + m * 4096);
  cptile(2, HIWF + m * 4096);
  cptile(3, HIWF + (16 + m) * 4096);
  cptile(4, CIWF + m * 4096);
  cptile(5, CIWF + (16 + m) * 4096);
  __syncthreads();

  { // e1 (VALU)
    const int r = tid;
    float xr[7];
#pragma unroll
    for (int k = 0; k < 7; ++k) xr[k] = x[(size_t)(g * 512 + r) * 7 + k];
    f16 ev[16];
#pragma unroll
    for (int i2 = 0; i2 < 16; ++i2) {
      const int c = 16 * m + i2;
      float a = eb1[c];
#pragma unroll
      for (int k = 0; k < 7; ++k) a += xr[k] * ew1[c * 7 + k];
      ev[i2] = (f16)fmaxf(a, 0.0f);
    }
    *(h8v*)(e1g + m * 8192 + r * 16)     = *(h8v*)&ev[0];
    *(h8v*)(e1g + m * 8192 + r * 16 + 8) = *(h8v*)&ev[8];
  }
  RELF(FE1, 1); WAITF(FE1, 1);

  { // e2 = relu(e1 @ ew2^T)
    const float bb = eb2[dcol];
#pragma unroll
    for (int mt = 0; mt < 4; ++mt) {
      const int R0 = wv * 64 + mt * 16;
      h8v a[8]; loadA8(e1g, R0, a);
      f4v acc = fzero();
#pragma unroll
      for (int k = 0; k < 8; ++k) acc = mfma16(a[k], BF(0, k), acc);
#pragma unroll
      for (int j = 0; j < 4; ++j)
        e2g[m * 8192 + (R0 + 4 * lg + j) * 16 + lr] = (f16)fmaxf(acc[j] + bb, 0.0f);
    }
  }
  RELF(FE2, 1); WAITF(FE2, 1);

  { // e3 = relu(e2 @ ew3^T)
    const float bb = eb3[dcol];
#pragma unroll
    for (int mt = 0; mt < 4; ++mt) {
      const int R0 = wv * 64 + mt * 16;
      h8v a[8]; loadA8(e2g, R0, a);
      f4v acc = fzero();
#pragma unroll
      for (int k = 0; k < 8; ++k) acc = mfma16(a[k], BF(1, k), acc);
#pragma unroll
      for (int j = 0; j < 4; ++j)
        e3g[m * 8192 + (R0 + 4 * lg + j) * 16 + lr] = (f16)fmaxf(acc[j] + bb, 0.0f);
    }
  }
  RELF(FE3, 1); WAITF(FE3, 1);

  // h/c init from e3
  float c0v[4][4], c1v[4][4];
  {
    f16* h0g0 = ws + H0F + g * 131072;   // parity-0 h0
    f16* h1g0 = ws + H1F + g * 131072;   // parity-0 h1
    const float bh0 = hib[dcol], bh1 = hib[256 + dcol];
    const float bc0 = cib[dcol], bc1 = cib[256 + dcol];
#pragma unroll
    for (int mt = 0; mt < 4; ++mt) {
      const int R0 = wv * 64 + mt * 16;
      h8v a[8]; loadA8(e3g, R0, a);
      f4v aH = fzero(), aC = fzero();
#pragma unroll
      for (int k = 0; k < 8; ++k) { aH = mfma16(a[k], BF(2, k), aH); aC = mfma16(a[k], BF(4, k), aC); }
#pragma unroll
      for (int j = 0; j < 4; ++j) {
        h0g0[m * 8192 + (R0 + 4 * lg + j) * 16 + lr] = (f16)(aH[j] + bh0);
        c0v[mt][j] = aC[j] + bc0;
      }
      aH = fzero(); aC = fzero();
#pragma unroll
      for (int k = 0; k < 8; ++k) { aH = mfma16(a[k], BF(3, k), aH); aC = mfma16(a[k], BF(5, k), aC); }
#pragma unroll
      for (int j = 0; j < 4; ++j) {
        h1g0[m * 8192 + (R0 + 4 * lg + j) * 16 + lr] = (f16)(aH[j] + bh1);
        c1v[mt][j] = aC[j] + bc1;
      }
    }
    if (tid < 32) { // dec(0) = start_token (parity 0, f32)
      f4v d; d[0] = stok[0]; d[1] = stok[1]; d[2] = stok[2]; d[3] = 0.f;
      *(f4v*)(decb + (m * 32 + tid) * 4) = d;
    }
  }
  RELF(FDEC, 1);

  // permanent weight tiles (W0, W1i, W1h; OW1 stays in global/L2)
#pragma unroll
  for (int G = 0; G < 4; ++G) {
    cptile(G,     W0F  + (G * 16 + m) * 4096);
    cptile(4 + G, W1IF + (G * 16 + m) * 4096);
    cptile(8 + G, W1HF + (G * 16 + m) * 4096);
  }
  __syncthreads();

  // ---- prologue: all init state visible; precompute g0(0) = h0(0) @ W0 ----
  f4v g0a[4][4];
  WAITF(FDEC, 1);
  {
    const f16* h0old0 = ws + H0F + g * 131072;   // parity 0
#pragma unroll
    for (int mt = 0; mt < 4; ++mt) {
      const int R0 = wv * 64 + mt * 16;
      h8v a[8]; loadA8(h0old0, R0, a);
#pragma unroll
      for (int G = 0; G < 4; ++G) g0a[mt][G] = fzero();
#pragma unroll
      for (int k = 0; k < 8; ++k) {
        g0a[mt][0] = mfma16(a[k], BF(0, k), g0a[mt][0]);
        g0a[mt][1] = mfma16(a[k], BF(1, k), g0a[mt][1]);
        g0a[mt][2] = mfma16(a[k], BF(2, k), g0a[mt][2]);
        g0a[mt][3] = mfma16(a[k], BF(3, k), g0a[mt][3]);
      }
    }
  }

  // ================= T = 200 sequential decoder steps =================
  // 3 syncs/step (FH0, FH1, FDEC). Cover schedule:
  //   FDEC <- g0 mt3 ; FH0 <- Phh mt0,1 ; FH1 <- g0 mt0,1.
#pragma unroll 1
  for (int t = 0; t < TT; ++t) {
    const int p = t & 1;
    f16* h0new = ws + H0F + ((p ^ 1) * 16 + g) * 131072;
    f16* h1old = ws + H1F + (p * 16 + g) * 131072;
    f16* h1new = ws + H1F + ((p ^ 1) * 16 + g) * 131072;
    const float* decp = decb + p * 2048;
    float* decn = decb + (p ^ 1) * 2048;

    // (A) dec ready (covered by g0 mt3 of previous iteration)
    WAITF(FDEC, t + 1);
    *(f4v*)(decsL + tid * 4) = *(const f4v*)(decp + tid * 4);
    __syncthreads();

    // (B) E0: consume g0a + decsL -> h0new
    {
      float cb0[4], cw[4][3];
#pragma unroll
      for (int G = 0; G < 4; ++G) {
        cb0[G]   = b0L[G * 16 + lr];
        cw[G][0] = wiL[(G * 16 + lr) * 3 + 0];
        cw[G][1] = wiL[(G * 16 + lr) * 3 + 1];
        cw[G][2] = wiL[(G * 16 + lr) * 3 + 2];
      }
#pragma unroll
      for (int mt = 0; mt < 4; ++mt) {
        const int R0 = wv * 64 + mt * 16;
#pragma unroll
        for (int j = 0; j < 4; ++j) {
          const int row = R0 + 4 * lg + j;
          f4v d4 = *(const f4v*)(decsL + row * 4);
          float gi = g0a[mt][0][j] + cb0[0] + d4[0]*cw[0][0] + d4[1]*cw[0][1] + d4[2]*cw[0][2];
          float gf = g0a[mt][1][j] + cb0[1] + d4[0]*cw[1][0] + d4[1]*cw[1][1] + d4[2]*cw[1][2];
          float gg = g0a[mt][2][j] + cb0[2] + d4[0]*cw[2][0] + d4[1]*cw[2][1] + d4[2]*cw[2][2];
          float go = g0a[mt][3][j] + cb0[3] + d4[0]*cw[3][0] + d4[1]*cw[3][1] + d4[2]*cw[3][2];
          float cn = sigm(gf) * c0v[mt][j] + sigm(gi) * tanh2(gg);
          c0v[mt][j] = cn;
          h0new[m * 8192 + row * 16 + lr] = (f16)(sigm(go) * tanh2(cn));
        }
      }
    }
    RELF(FH0, t + 1);

    // (C) Phh mt0,1 = h1old @ W1h : covers the FH0 wait
    f4v ph[2][4];
#pragma unroll
    for (int mt = 0; mt < 2; ++mt) {
      const int R0 = wv * 64 + mt * 16;
      h8v a[8]; loadA8(h1old, R0, a);
#pragma unroll
      for (int G = 0; G < 4; ++G) ph[mt][G] = fzero();
#pragma unroll
      for (int k = 0; k < 8; ++k) {
        ph[mt][0] = mfma16(a[k], BF(8,  k), ph[mt][0]);
        ph[mt][1] = mfma16(a[k], BF(9,  k), ph[mt][1]);
        ph[mt][2] = mfma16(a[k], BF(10, k), ph[mt][2]);
        ph[mt][3] = mfma16(a[k], BF(11, k), ph[mt][3]);
      }
    }
    WAITF(FH0, t + 1);

    // (D) L1
    {
      float cb1[4];
#pragma unroll
      for (int G = 0; G < 4; ++G) cb1[G] = b1L[G * 16 + lr];
      // mt 0,1: += W1i, then elementwise
#pragma unroll
      for (int mt = 0; mt < 2; ++mt) {
        const int R0 = wv * 64 + mt * 16;
        h8v a[8]; loadA8(h0new, R0, a);
#pragma unroll
        for (int k = 0; k < 8; ++k) {
          ph[mt][0] = mfma16(a[k], BF(4, k), ph[mt][0]);
          ph[mt][1] = mfma16(a[k], BF(5, k), ph[mt][1]);
          ph[mt][2] = mfma16(a[k], BF(6, k), ph[mt][2]);
          ph[mt][3] = mfma16(a[k], BF(7, k), ph[mt][3]);
        }
#pragma unroll
        for (int j = 0; j < 4; ++j) {
          const int row = R0 + 4 * lg + j;
          float cn = sigm(ph[mt][1][j] + cb1[1]) * c1v[mt][j]
                   + sigm(ph[mt][0][j] + cb1[0]) * tanh2(ph[mt][2][j] + cb1[2]);
          c1v[mt][j] = cn;
          h1new[m * 8192 + row * 16 + lr] = (f16)(sigm(ph[mt][3][j] + cb1[3]) * tanh2(cn));
        }
      }
      // mt 2,3: fresh accumulators, W1h + W1i
#pragma unroll
      for (int mt = 2; mt < 4; ++mt) {
        const int R0 = wv * 64 + mt * 16;
        f4v ai = fzero(), af = fzero(), ag = fzero(), ao = fzero();
        {
          h8v a[8]; loadA8(h1old, R0, a);
#pragma unroll
          for (int k = 0; k < 8; ++k) {
            ai = mfma16(a[k], BF(8,  k), ai);
            af = mfma16(a[k], BF(9,  k), af);
            ag = mfma16(a[k], BF(10, k), ag);
            ao = mfma16(a[k], BF(11, k), ao);
          }
        }
        {
          h8v a[8]; loadA8(h0new, R0, a);
#pragma unroll
          for (int k = 0; k < 8; ++k) {
            ai = mfma16(a[k], BF(4, k), ai);
            af = mfma16(a[k], BF(5, k), af);
            ag = mfma16(a[k], BF(6, k), ag);
            ao = mfma16(a[k], BF(7, k), ao);
          }
        }
#pragma unroll
        for (int j = 0; j < 4; ++j) {
          const int row = R0 + 4 * lg + j;
          float cn = sigm(af[j] + cb1[1]) * c1v[mt][j]
                   + sigm(ai[j] + cb1[0]) * tanh2(ag[j] + cb1[2]);
          c1v[mt][j] = cn;
          h1new[m * 8192 + row * 16 + lr] = (f16)(sigm(ao[j] + cb1[3]) * tanh2(cn));
        }
      }
    }
    RELF(FH1, t + 1);

    // (E) g0(t+1) mt0,1 = h0new @ W0 : covers the FH1 wait
#pragma unroll
    for (int mt = 0; mt < 2; ++mt) {
      const int R0 = wv * 64 + mt * 16;
      h8v a[8]; loadA8(h0new, R0, a);
#pragma unroll
      for (int G = 0; G < 4; ++G) g0a[mt][G] = fzero();
#pragma unroll
      for (int k = 0; k < 8; ++k) {
        g0a[mt][0] = mfma16(a[k], BF(0, k), g0a[mt][0]);
        g0a[mt][1] = mfma16(a[k], BF(1, k), g0a[mt][1]);
        g0a[mt][2] = mfma16(a[k], BF(2, k), g0a[mt][2]);
        g0a[mt][3] = mfma16(a[k], BF(3, k), g0a[mt][3]);
      }
    }
    WAITF(FH1, t + 1);

    // (F) head: o1 = relu(h1new[own 32 rows] @ ow1^T + ob1) -> o1s (LDS, f32).
    //     Wave wv owns o1 col-tile wv; OW1 read from global (immutable, L2-hot).
    {
      const h8v* OW1G = (const h8v*)(ws + OW1F);
#pragma unroll
      for (int mt = 0; mt < 2; ++mt) {
        h8v a[8]; loadA8(h1new, m * 32 + mt * 16, a);
        f4v oacc = fzero();
#pragma unroll
        for (int k = 0; k < 8; ++k)
          oacc = mfma16(a[k], OW1G[(wv << 9) + (((k << 2) + lg) << 4) + lr], oacc);
        const float bo = ob1L[(wv << 4) + lr];
#pragma unroll
        for (int j = 0; j < 4; ++j)
          o1s[(mt * 16 + 4 * lg + j) * 132 + (wv << 4) + lr] = fmaxf(oacc[j] + bo, 0.0f);
      }
    }

    // (G) g0(t+1) mt2 rebuild (before the LDS barrier; independent of o1s)
    {
      const int R0 = wv * 64 + 2 * 16;
      h8v a[8]; loadA8(h0new, R0, a);
#pragma unroll
      for (int G = 0; G < 4; ++G) g0a[2][G] = fzero();
#pragma unroll
      for (int k = 0; k < 8; ++k) {
        g0a[2][0] = mfma16(a[k], BF(0, k), g0a[2][0]);
        g0a[2][1] = mfma16(a[k], BF(1, k), g0a[2][1]);
        g0a[2][2] = mfma16(a[k], BF(2, k), g0a[2][2]);
        g0a[2][3] = mfma16(a[k], BF(3, k), g0a[2][3]);
      }
    }
    __syncthreads();   // o1s visible

    // (H) dec GEMV over own 32 rows; write out + decn (global exchange)
    {
      const int r = tid >> 4, jj = tid & 15;   // 32 rows x 16 threads
      float a0 = 0.f, a1 = 0.f, a2 = 0.f;
#pragma unroll
      for (int kk = 0; kk < 8; ++kk) {
        const int k = jj * 8 + kk;
        const float ov = o1s[r * 132 + k];
        a0 += ov * w2s[k];
        a1 += ov * w2s[128 + k];
        a2 += ov * w2s[256 + k];
      }
#pragma unroll
      for (int s = 8; s >= 1; s >>= 1) {
        a0 += __shfl_xor(a0, s);
        a1 += __shfl_xor(a1, s);
        a2 += __shfl_xor(a2, s);
      }
      if (jj == 0) {
        a0 += ob2s[0]; a1 += ob2s[1]; a2 += ob2s[2];
        const int row = m * 32 + r;
        float* op = out + ((size_t)(g * 512 + row) * TT + t) * 3;
        op[0] = a0; op[1] = a1; op[2] = a2;
        f4v d; d[0] = a0; d[1] = a1; d[2] = a2; d[3] = 0.f;
        *(f4v*)(decn + row * 4) = d;
      }
    }
    RELF(FDEC, t + 2);

    // (I) g0(t+1) mt3 : covers the next iteration's FDEC wait
    {
      const int R0 = wv * 64 + 3 * 16;
      h8v a[8]; loadA8(h0new, R0, a);
#pragma unroll
      for (int G = 0; G < 4; ++G) g0a[3][G] = fzero();
#pragma unroll
      for (int k = 0; k < 8; ++k) {
        g0a[3][0] = mfma16(a[k], BF(0, k), g0a[3][0]);
        g0a[3][1] = mfma16(a[k], BF(1, k), g0a[3][1]);
        g0a[3][2] = mfma16(a[k], BF(2, k), g0a[3][2]);
        g0a[3][3] = mfma16(a[k], BF(3, k), g0a[3][3]);
      }
    }
  }
}

extern "C" void kernel_launch(void* const* d_in, const int* in_sizes, int n_in,
                              void* d_out, int out_size, void* d_ws, size_t ws_size,
                              hipStream_t stream) {
  (void)in_sizes; (void)n_in; (void)out_size; (void)ws_size;
  f16* wk = (f16*)d_ws;
  int* flags = (int*)((char*)d_ws + (size_t)FLGF * 2);
  conv_w<<<(FRAG_TOTAL + 255) / 256, 256, 0, stream>>>(
      (const float*)d_in[12], (const float*)d_in[15],
      (const float*)d_in[16], (const float*)d_in[19],
      (const float*)d_in[3],  (const float*)d_in[5],
      (const float*)d_in[7],  (const float*)d_in[9],
      wk, flags);
  traj_kernel<<<NWG, NTHR, 0, stream>>>(
      (const float*)d_in[0],
      (const float*)d_in[1],  (const float*)d_in[2],
      (const float*)d_in[4],  (const float*)d_in[6],
      (const float*)d_in[8],  (const float*)d_in[10],
      (const float*)d_in[11],
      (const float*)d_in[13], (const float*)d_in[14],
      (const float*)d_in[17], (const float*)d_in[18],
      (const float*)d_in[20], (const float*)d_in[21],
      (const float*)d_in[22], (const float*)d_in[23],
      wk, flags, (float*)d_out);
}